// Round 3
// baseline (982.137 us; speedup 1.0000x reference)
//
#include <hip/hip_runtime.h>
#include <math.h>

#define H      1024
#define NA     512
#define NI     256
#define SEQ    4096
#define BATCH  4
#define NTOK   (BATCH*SEQ)      // 16384
#define MTOK   32               // tokens per block in score kernel
#define KC     64               // K chunk staged in LDS
#define PT     33               // padded token stride: 2-way write conflicts (free), broadcast reads
#define NCHUNK (H / KC)         // 16
#define SINKN  4
#define RECENTN 19
#define MIDN   (SEQ - SINKN - RECENTN)   // 4073
#define KSEL   2025
#define CHK    16               // per-thread contiguous chunk in select kernel

// ---------------------------------------------------------------------------
// Kernel 1: fused two-layer MLP scores for att (keys) and imp (values).
// block = 256 threads, 32 tokens/block (512 blocks -> 2 blocks/CU).
// Thread (to=tid&63, tt=tid>>6): att units {to*4..+3} and {256+to*4..+3},
// imp units {to*4..+3}, tokens {tt*8..+7}. 96 fp32 accumulators/thread.
// Double-buffered LDS staging: next chunk's global loads issued before the
// inner loop, stored after it; one barrier per chunk.
// ---------------------------------------------------------------------------
__global__ __launch_bounds__(256, 2) void score_kernel(
    const float* __restrict__ keys, const float* __restrict__ values,
    const float* __restrict__ W1a, const float* __restrict__ b1a,
    const float* __restrict__ W2a, const float* __restrict__ b2a,
    const float* __restrict__ W1i, const float* __restrict__ b1i,
    const float* __restrict__ W2i, const float* __restrict__ b2i,
    float* __restrict__ scores)
{
    // per buffer: k KC*PT + v KC*PT = 4224 floats; 2 buffers = 33792 B
    __shared__ __align__(16) float smem[2 * 2 * KC * PT];

    const int tid  = threadIdx.x;
    const int to   = tid & 63;
    const int tt   = tid >> 6;
    const int tokb = blockIdx.x * MTOK;

    float accA0[4][8], accA1[4][8], accI[4][8];
#pragma unroll
    for (int j = 0; j < 4; ++j)
#pragma unroll
        for (int t = 0; t < 8; ++t) { accA0[j][t] = 0.f; accA1[j][t] = 0.f; accI[j][t] = 0.f; }

    // staging map: thread -> token tm = tid>>3, float4 slots q and q+8 of the 64-float chunk
    const int tm = tid >> 3;
    const int q  = tid & 7;
    const float* krow = keys   + (size_t)(tokb + tm) * H;
    const float* vrow = values + (size_t)(tokb + tm) * H;

    const float* wa_base = W1a + to * 4;
    const float* wi_base = W1i + to * 4;

    // ---- stage chunk 0 into buffer 0 ----
    {
        float4 ka = *(const float4*)(krow + q * 4);
        float4 kb = *(const float4*)(krow + (q + 8) * 4);
        float4 va = *(const float4*)(vrow + q * 4);
        float4 vb = *(const float4*)(vrow + (q + 8) * 4);
        float* k_lds = smem;                 // buffer 0
        float* v_lds = smem + KC * PT;
        k_lds[(q * 4 + 0) * PT + tm] = ka.x;
        k_lds[(q * 4 + 1) * PT + tm] = ka.y;
        k_lds[(q * 4 + 2) * PT + tm] = ka.z;
        k_lds[(q * 4 + 3) * PT + tm] = ka.w;
        k_lds[((q + 8) * 4 + 0) * PT + tm] = kb.x;
        k_lds[((q + 8) * 4 + 1) * PT + tm] = kb.y;
        k_lds[((q + 8) * 4 + 2) * PT + tm] = kb.z;
        k_lds[((q + 8) * 4 + 3) * PT + tm] = kb.w;
        v_lds[(q * 4 + 0) * PT + tm] = va.x;
        v_lds[(q * 4 + 1) * PT + tm] = va.y;
        v_lds[(q * 4 + 2) * PT + tm] = va.z;
        v_lds[(q * 4 + 3) * PT + tm] = va.w;
        v_lds[((q + 8) * 4 + 0) * PT + tm] = vb.x;
        v_lds[((q + 8) * 4 + 1) * PT + tm] = vb.y;
        v_lds[((q + 8) * 4 + 2) * PT + tm] = vb.z;
        v_lds[((q + 8) * 4 + 3) * PT + tm] = vb.w;
    }
    __syncthreads();

    for (int c = 0; c < NCHUNK; ++c) {
        const int h0 = c * KC;

        // issue next chunk's global loads (latency hidden under the inner loop)
        float4 nka, nkb, nva, nvb;
        if (c + 1 < NCHUNK) {
            nka = *(const float4*)(krow + h0 + KC + q * 4);
            nkb = *(const float4*)(krow + h0 + KC + (q + 8) * 4);
            nva = *(const float4*)(vrow + h0 + KC + q * 4);
            nvb = *(const float4*)(vrow + h0 + KC + (q + 8) * 4);
        }

        const float* k_lds = smem + (size_t)(c & 1) * (2 * KC * PT);
        const float* v_lds = k_lds + KC * PT;
        const float* wa_p = wa_base + (size_t)h0 * NA;
        const float* wi_p = wi_base + (size_t)h0 * NI;

#pragma unroll 4
        for (int h = 0; h < KC; ++h) {
            float kf[8], vf[8], wa[8], wi4[4];
            *(float4*)&kf[0]  = *(const float4*)&k_lds[h * PT + tt * 8];
            *(float4*)&kf[4]  = *(const float4*)&k_lds[h * PT + tt * 8 + 4];
            *(float4*)&vf[0]  = *(const float4*)&v_lds[h * PT + tt * 8];
            *(float4*)&vf[4]  = *(const float4*)&v_lds[h * PT + tt * 8 + 4];
            *(float4*)&wa[0]  = *(const float4*)(wa_p + (size_t)h * NA);
            *(float4*)&wa[4]  = *(const float4*)(wa_p + (size_t)h * NA + 256);
            *(float4*)&wi4[0] = *(const float4*)(wi_p + (size_t)h * NI);
#pragma unroll
            for (int j = 0; j < 4; ++j)
#pragma unroll
                for (int t = 0; t < 8; ++t) {
                    accA0[j][t] = fmaf(kf[t], wa[j],     accA0[j][t]);
                    accA1[j][t] = fmaf(kf[t], wa[4 + j], accA1[j][t]);
                    accI[j][t]  = fmaf(vf[t], wi4[j],    accI[j][t]);
                }
        }

        // store next chunk into the other buffer, then one barrier
        if (c + 1 < NCHUNK) {
            float* dk = smem + (size_t)((c + 1) & 1) * (2 * KC * PT);
            float* dv = dk + KC * PT;
            dk[(q * 4 + 0) * PT + tm] = nka.x;
            dk[(q * 4 + 1) * PT + tm] = nka.y;
            dk[(q * 4 + 2) * PT + tm] = nka.z;
            dk[(q * 4 + 3) * PT + tm] = nka.w;
            dk[((q + 8) * 4 + 0) * PT + tm] = nkb.x;
            dk[((q + 8) * 4 + 1) * PT + tm] = nkb.y;
            dk[((q + 8) * 4 + 2) * PT + tm] = nkb.z;
            dk[((q + 8) * 4 + 3) * PT + tm] = nkb.w;
            dv[(q * 4 + 0) * PT + tm] = nva.x;
            dv[(q * 4 + 1) * PT + tm] = nva.y;
            dv[(q * 4 + 2) * PT + tm] = nva.z;
            dv[(q * 4 + 3) * PT + tm] = nva.w;
            dv[((q + 8) * 4 + 0) * PT + tm] = nvb.x;
            dv[((q + 8) * 4 + 1) * PT + tm] = nvb.y;
            dv[((q + 8) * 4 + 2) * PT + tm] = nvb.z;
            dv[((q + 8) * 4 + 3) * PT + tm] = nvb.w;
        }
        __syncthreads();
    }

    // ---- epilogue: second layers ----
    float b1aA[8], w2aA[8], b1iA[4], w2iA[4];
    *(float4*)&b1aA[0] = *(const float4*)(b1a + to * 4);
    *(float4*)&b1aA[4] = *(const float4*)(b1a + 256 + to * 4);
    *(float4*)&w2aA[0] = *(const float4*)(W2a + to * 4);
    *(float4*)&w2aA[4] = *(const float4*)(W2a + 256 + to * 4);
    *(float4*)&b1iA[0] = *(const float4*)(b1i + to * 4);
    *(float4*)&w2iA[0] = *(const float4*)(W2i + to * 4);

    float* red_a = smem;                  // [32][65] padded = 2080 floats
    float* red_i = smem + 32 * 65;

#pragma unroll
    for (int t = 0; t < 8; ++t) {
        float pa = 0.f, pi = 0.f;
#pragma unroll
        for (int j = 0; j < 4; ++j) {
            pa += fmaxf(accA0[j][t] + b1aA[j],     0.f) * w2aA[j];
            pa += fmaxf(accA1[j][t] + b1aA[4 + j], 0.f) * w2aA[4 + j];
            pi += fmaxf(accI[j][t]  + b1iA[j],     0.f) * w2iA[j];
        }
        const int tg = tt * 8 + t;
        red_a[tg * 65 + to] = pa;
        red_i[tg * 65 + to] = pi;
    }
    __syncthreads();
    if (tid < MTOK) {
        float sa = 0.f, si = 0.f;
        for (int j2 = 0; j2 < 64; ++j2) {
            sa += red_a[tid * 65 + j2];
            si += red_i[tid * 65 + j2];
        }
        const float att = 1.f / (1.f + expf(-(sa + b2a[0])));
        scores[tokb + tid] = 0.6f * att + 0.4f * (si + b2i[0]);
    }
}

// ---------------------------------------------------------------------------
// block-wide sum (256 threads), result broadcast to all threads
// ---------------------------------------------------------------------------
__device__ __forceinline__ int block_sum(int val, int* red, int tid)
{
#pragma unroll
    for (int off = 32; off > 0; off >>= 1) val += __shfl_down(val, off);
    if ((tid & 63) == 0) red[tid >> 6] = val;
    __syncthreads();
    const int total = red[0] + red[1] + red[2] + red[3];
    __syncthreads();
    return total;
}

// ---------------------------------------------------------------------------
// Kernel 2: per-row exact top-KSEL of the 4073 middle scores -> float mask.
// 4-pass byte-radix select (256-bin LDS histogram) on sign-flipped uint keys;
// ties kept lowest-index first (top_k semantics). One block per batch row.
// ---------------------------------------------------------------------------
__global__ __launch_bounds__(256) void select_kernel(
    const float* __restrict__ scores, float* __restrict__ mask)
{
    __shared__ unsigned int ks[MIDN];
    __shared__ int hist[256];
    __shared__ int red[4];
    __shared__ int scan_s[256];
    __shared__ unsigned int sh_pref;
    __shared__ int sh_r;

    const int tid = threadIdx.x;
    const int row = blockIdx.x;
    const float* sr = scores + row * SEQ;

    for (int i = tid; i < MIDN; i += 256) {
        unsigned int u = __float_as_uint(sr[SINKN + i]);
        u = (u & 0x80000000u) ? ~u : (u | 0x80000000u);   // order-preserving map
        ks[i] = u;
    }
    if (tid == 0) { sh_pref = 0u; sh_r = KSEL; }
    __syncthreads();

    // byte-radix: after 4 passes sh_pref == KSEL-th largest key value
    for (int b = 3; b >= 0; --b) {
        hist[tid] = 0;
        __syncthreads();
        const unsigned int hi_mask = (b == 3) ? 0u : (0xFFFFFFFFu << ((b + 1) * 8));
        const unsigned int pref = sh_pref;
        for (int i = tid; i < MIDN; i += 256) {
            const unsigned int u = ks[i];
            if ((u & hi_mask) == pref)
                atomicAdd(&hist[(u >> (b * 8)) & 255], 1);
        }
        __syncthreads();
        if (tid == 0) {
            int r = sh_r, cum = 0, d = 255;
            for (; d >= 0; --d) {
                cum += hist[d];
                if (cum >= r) break;
            }
            sh_r = r - (cum - hist[d]);
            sh_pref = sh_pref | ((unsigned int)d << (b * 8));
        }
        __syncthreads();
    }
    const unsigned int v = sh_pref;

    const int st = tid * CHK;
    const int en = (st + CHK < MIDN) ? (st + CHK) : MIDN;

    int cgt = 0, ceq = 0;
    for (int k = st; k < en; ++k) { cgt += (ks[k] > v) ? 1 : 0; ceq += (ks[k] == v) ? 1 : 0; }
    const int total_gt = block_sum(cgt, red, tid);
    const int need = KSEL - total_gt;      // #ties to keep (>=1 by construction)

    scan_s[tid] = ceq;
    __syncthreads();
    if (tid == 0) {                        // exclusive scan of 256 tie counts
        int run = 0;
        for (int i = 0; i < 256; ++i) { const int t = scan_s[i]; scan_s[i] = run; run += t; }
    }
    __syncthreads();

    float* mr = mask + row * SEQ;
    int r = scan_s[tid];
    for (int k = st; k < en; ++k) {
        const unsigned int u = ks[k];
        bool keep = false;
        if (u > v) keep = true;
        else if (u == v) { keep = (r < need); ++r; }
        mr[SINKN + k] = keep ? 1.f : 0.f;
    }
    for (int s = tid; s < SEQ; s += 256) {
        if (s < SINKN || s >= SEQ - RECENTN) mr[s] = 1.f;
    }
}

// ---------------------------------------------------------------------------
// Kernel 3: out = concat(keys*mask, values*mask), float4 grid-stride.
// ---------------------------------------------------------------------------
__global__ __launch_bounds__(256) void apply_kernel(
    const float* __restrict__ keys, const float* __restrict__ values,
    const float* __restrict__ mask, float* __restrict__ out)
{
    const int QT = NTOK * H / 4;          // 4194304 float4 per tensor
    const int stride = gridDim.x * 256;
    for (int i4 = blockIdx.x * 256 + threadIdx.x; i4 < 2 * QT; i4 += stride) {
        const bool isv = (i4 >= QT);
        const int  j4  = isv ? (i4 - QT) : i4;
        const float m  = mask[j4 >> 8];   // 256 float4 per token row
        const float4* src = isv ? (const float4*)values : (const float4*)keys;
        const float4 x = src[j4];
        float4 y; y.x = x.x * m; y.y = x.y * m; y.z = x.z * m; y.w = x.w * m;
        ((float4*)out)[i4] = y;
    }
}

extern "C" void kernel_launch(void* const* d_in, const int* in_sizes, int n_in,
                              void* d_out, int out_size, void* d_ws, size_t ws_size,
                              hipStream_t stream)
{
    const float* keys   = (const float*)d_in[0];
    const float* values = (const float*)d_in[1];
    const float* W1a = (const float*)d_in[2];
    const float* b1a = (const float*)d_in[3];
    const float* W2a = (const float*)d_in[4];
    const float* b2a = (const float*)d_in[5];
    const float* W1i = (const float*)d_in[6];
    const float* b1i = (const float*)d_in[7];
    const float* W2i = (const float*)d_in[8];
    const float* b2i = (const float*)d_in[9];

    float* scores = (float*)d_ws;          // NTOK floats
    float* mask   = scores + NTOK;         // NTOK floats

    score_kernel<<<NTOK / MTOK, 256, 0, stream>>>(keys, values, W1a, b1a, W2a, b2a,
                                                  W1i, b1i, W2i, b2i, scores);
    select_kernel<<<BATCH, 256, 0, stream>>>(scores, mask);
    apply_kernel<<<8192, 256, 0, stream>>>(keys, values, mask, (float*)d_out);
}